// Round 1
// baseline (147.724 us; speedup 1.0000x reference)
//
#include <hip/hip_runtime.h>

typedef __bf16 bf16x8 __attribute__((ext_vector_type(8)));
typedef float floatx4 __attribute__((ext_vector_type(4)));
typedef unsigned short ushortx8 __attribute__((ext_vector_type(8)));
typedef unsigned short ushortx4 __attribute__((ext_vector_type(4)));
typedef unsigned short ushort_t;

// ---- constants (from reference) ----
#define SB 2048      // sequence length
#define EB 1024      // embed
#define HB 16        // heads
#define DB 64        // head dim
#define QT 64        // queries per attention block
#define KBAND 192    // key slots per 64-query tile (64 halo each side)
#define KROW 72      // padded K lds row (bf16 elems) -> 144 B, 16B-aligned, 2-way banks
#define VROW 200     // padded Vt/P lds row -> 400 B, 16B-aligned, 2-way banks

__device__ __forceinline__ ushort_t f2bf(float f) {
    union { float f; unsigned int u; } v; v.f = f;
    unsigned int r = v.u + 0x7fffu + ((v.u >> 16) & 1u);   // RNE
    return (ushort_t)(r >> 16);
}

union BF8 { ushortx8 u; bf16x8 b; };

// ============================ w_out -> bf16 ============================
__global__ __launch_bounds__(256) void cvtw_kernel(const float* __restrict__ w,
                                                   ushort_t* __restrict__ wb) {
    int i = blockIdx.x * 256 + threadIdx.x;          // over E*E/4 float4s
    const float4 v = ((const float4*)w)[i];
    ushortx4 o;
    o.x = f2bf(v.x); o.y = f2bf(v.y); o.z = f2bf(v.z); o.w = f2bf(v.w);
    ((ushortx4*)wb)[i] = o;
}

// ============================ attention ============================
// grid: B*H*(S/QT) = 2*16*32 = 1024 blocks, 256 threads (4 waves).
// wave w handles queries [q0+16w, q0+16w+16).
__global__ __launch_bounds__(256) void attn_kernel(const float* __restrict__ Vg,
                                                   const float* __restrict__ Kg,
                                                   const float* __restrict__ Qg,
                                                   ushort_t* __restrict__ Xg) {
    __shared__ ushort_t Klds[KBAND * KROW];   // 27648 B; reused as P after scores
    __shared__ ushort_t Vt[DB * VROW];        // 25600 B (V transposed: [dim][key])

    const int tid  = threadIdx.x;
    const int wave = tid >> 6;
    const int lane = tid & 63;
    const int l15  = lane & 15;
    const int l4   = lane >> 4;

    const int qt = blockIdx.x & 31;
    const int h  = (blockIdx.x >> 5) & 15;
    const int b  = blockIdx.x >> 9;

    const int q0     = qt * QT;
    const int kstart = q0 - 64;

    const float* Kbase = Kg + ((size_t)b * SB) * EB + h * DB;
    const float* Vbase = Vg + ((size_t)b * SB) * EB + h * DB;

    // ---- stage K band (row-major) and V band (transposed) into LDS as bf16 ----
    #pragma unroll
    for (int it = 0; it < (KBAND * DB / 4) / 256; ++it) {   // 12 iters of float4
        int idx = it * 256 + tid;
        int j   = idx >> 4;            // key slot 0..191
        int d4  = (idx & 15) * 4;      // dim 0..60
        int kk  = kstart + j;
        float4 kv = make_float4(0.f, 0.f, 0.f, 0.f);
        float4 vv = make_float4(0.f, 0.f, 0.f, 0.f);
        if (kk >= 0 && kk < SB) {
            kv = *(const float4*)(Kbase + (size_t)kk * EB + d4);
            vv = *(const float4*)(Vbase + (size_t)kk * EB + d4);
        }
        ushortx4 ku;
        ku.x = f2bf(kv.x); ku.y = f2bf(kv.y); ku.z = f2bf(kv.z); ku.w = f2bf(kv.w);
        *(ushortx4*)(Klds + j * KROW + d4) = ku;
        Vt[(d4 + 0) * VROW + j] = f2bf(vv.x);
        Vt[(d4 + 1) * VROW + j] = f2bf(vv.y);
        Vt[(d4 + 2) * VROW + j] = f2bf(vv.z);
        Vt[(d4 + 3) * VROW + j] = f2bf(vv.w);
    }

    // ---- Q fragments straight from global (A-layout: m=l15, k=l4*8+j) ----
    const int qrow = q0 + wave * 16 + l15;
    const float* Qrow = Qg + ((size_t)b * SB + qrow) * EB + h * DB;
    bf16x8 qfrag[2];
    #pragma unroll
    for (int ks = 0; ks < 2; ++ks) {
        const float4* p = (const float4*)(Qrow + ks * 32 + l4 * 8);
        float4 a0 = p[0], a1 = p[1];
        BF8 t;
        t.u[0] = f2bf(a0.x); t.u[1] = f2bf(a0.y); t.u[2] = f2bf(a0.z); t.u[3] = f2bf(a0.w);
        t.u[4] = f2bf(a1.x); t.u[5] = f2bf(a1.y); t.u[6] = f2bf(a1.z); t.u[7] = f2bf(a1.w);
        qfrag[ks] = t.b;
    }

    __syncthreads();

    // ---- S = Q K^T : M=16 (queries), N=192 (keys, 12 tiles), K=64 (2 steps) ----
    floatx4 sfrag[12];
    #pragma unroll
    for (int nt = 0; nt < 12; ++nt) {
        floatx4 acc = {0.f, 0.f, 0.f, 0.f};
        #pragma unroll
        for (int ks = 0; ks < 2; ++ks) {
            bf16x8 kf = *(const bf16x8*)(Klds + (nt * 16 + l15) * KROW + ks * 32 + l4 * 8);
            acc = __builtin_amdgcn_mfma_f32_16x16x32_bf16(qfrag[ks], kf, acc, 0, 0, 0);
        }
        sfrag[nt] = acc;
    }

    // ---- mask + scale; softmax per row (row = wave*16 + l4*4 + r, cols across 16 lanes) ----
    const float scale = 0.03125f;   // 1/sqrt(1024)
    #pragma unroll
    for (int nt = 0; nt < 12; ++nt) {
        int j = nt * 16 + l15;
        int kk = kstart + j;
        #pragma unroll
        for (int r = 0; r < 4; ++r) {
            int m = wave * 16 + l4 * 4 + r;   // query index within 64-tile
            bool valid = (j >= m) && (j <= m + 128) && (kk >= 0) && (kk < SB);
            float s = sfrag[nt][r] * scale;
            sfrag[nt][r] = valid ? s : -1e30f;
        }
    }
    #pragma unroll
    for (int r = 0; r < 4; ++r) {
        float mx = -1e30f;
        #pragma unroll
        for (int nt = 0; nt < 12; ++nt) mx = fmaxf(mx, sfrag[nt][r]);
        mx = fmaxf(mx, __shfl_xor(mx, 1));
        mx = fmaxf(mx, __shfl_xor(mx, 2));
        mx = fmaxf(mx, __shfl_xor(mx, 4));
        mx = fmaxf(mx, __shfl_xor(mx, 8));
        float sum = 0.f;
        #pragma unroll
        for (int nt = 0; nt < 12; ++nt) {
            float e = __expf(sfrag[nt][r] - mx);
            sfrag[nt][r] = e;
            sum += e;
        }
        sum += __shfl_xor(sum, 1);
        sum += __shfl_xor(sum, 2);
        sum += __shfl_xor(sum, 4);
        sum += __shfl_xor(sum, 8);
        float inv = 1.f / sum;
        #pragma unroll
        for (int nt = 0; nt < 12; ++nt) sfrag[nt][r] *= inv;
    }

    // ---- P: C/D layout -> A layout via LDS (overlay K region, per-wave) ----
    __syncthreads();                              // all waves done reading Klds
    ushort_t* Pw = Klds + wave * (16 * VROW);     // 16 rows x 200 per wave
    #pragma unroll
    for (int nt = 0; nt < 12; ++nt)
        #pragma unroll
        for (int r = 0; r < 4; ++r)
            Pw[(l4 * 4 + r) * VROW + nt * 16 + l15] = f2bf(sfrag[nt][r]);
    __syncthreads();

    // ---- O = P V : M=16, N=64 (4 tiles), K=192 (6 steps) ----
    #pragma unroll
    for (int nt = 0; nt < 4; ++nt) {
        floatx4 acc = {0.f, 0.f, 0.f, 0.f};
        #pragma unroll
        for (int ks = 0; ks < 6; ++ks) {
            bf16x8 pf = *(const bf16x8*)(Pw + l15 * VROW + ks * 32 + l4 * 8);
            bf16x8 vf = *(const bf16x8*)(Vt + (nt * 16 + l15) * VROW + ks * 32 + l4 * 8);
            acc = __builtin_amdgcn_mfma_f32_16x16x32_bf16(pf, vf, acc, 0, 0, 0);
        }
        // write X (bf16) in (B,S,E) layout: row = q, col = h*64 + nt*16 + l15
        #pragma unroll
        for (int r = 0; r < 4; ++r) {
            int q  = q0 + wave * 16 + l4 * 4 + r;
            int dd = h * DB + nt * 16 + l15;
            Xg[((size_t)b * SB + q) * EB + dd] = f2bf(acc[r]);
        }
    }
}

// ============================ projection GEMM ============================
// out[i][o] = sum_k X[i][k] * W[o][k] + bias[o]
// M=4096, N=1024, K=1024. Tiles: BM=BN=128, BK=32. 256 blocks x 512 threads (8 waves).
__device__ __forceinline__ void async_load16(const void* g, void* l) {
    __builtin_amdgcn_global_load_lds((__attribute__((address_space(1))) void*)g,
                                     (__attribute__((address_space(3))) void*)l,
                                     16, 0, 0);
}

__global__ __launch_bounds__(512) void proj_kernel(const ushort_t* __restrict__ X,
                                                   const ushort_t* __restrict__ Wb,
                                                   const float* __restrict__ bias,
                                                   float* __restrict__ out) {
    __shared__ ushort_t As[128 * 32];   // 8192 B
    __shared__ ushort_t Bs[128 * 32];   // 8192 B

    const int tid  = threadIdx.x;
    const int wave = tid >> 6;
    const int lane = tid & 63;
    const int l15  = lane & 15;
    const int l4   = lane >> 4;

    const int m0 = blockIdx.x * 128;
    const int n0 = blockIdx.y * 128;
    const int wm = (wave >> 2) * 64;    // 2 wave-rows
    const int wn = (wave & 3) * 32;     // 4 wave-cols

    floatx4 acc[4][2];
    #pragma unroll
    for (int i = 0; i < 4; ++i)
        #pragma unroll
        for (int j = 0; j < 2; ++j)
            acc[i][j] = (floatx4){0.f, 0.f, 0.f, 0.f};

    // staging: chunk c = tid (0..511): row = c>>2, col = (c&3)*8
    const int crow = tid >> 2;
    const int ccol = (tid & 3) * 8;
    const ushort_t* gA = X  + (size_t)(m0 + crow) * EB + ccol;
    const ushort_t* gB = Wb + (size_t)(n0 + crow) * EB + ccol;
    ushort_t* lA = As + wave * 512;     // wave-uniform; lane lands at +lane*16B
    ushort_t* lB = Bs + wave * 512;

    for (int kt = 0; kt < EB / 32; ++kt) {
        async_load16(gA, lA);
        async_load16(gB, lB);
        gA += 32; gB += 32;
        __syncthreads();                // drains vmcnt -> LDS valid

        bf16x8 af[4], bf[2];
        #pragma unroll
        for (int i = 0; i < 4; ++i)
            af[i] = *(const bf16x8*)(As + (wm + i * 16 + l15) * 32 + l4 * 8);
        #pragma unroll
        for (int j = 0; j < 2; ++j)
            bf[j] = *(const bf16x8*)(Bs + (wn + j * 16 + l15) * 32 + l4 * 8);
        #pragma unroll
        for (int i = 0; i < 4; ++i)
            #pragma unroll
            for (int j = 0; j < 2; ++j)
                acc[i][j] = __builtin_amdgcn_mfma_f32_16x16x32_bf16(af[i], bf[j], acc[i][j], 0, 0, 0);
        __syncthreads();                // done reading before next stage
    }

    #pragma unroll
    for (int i = 0; i < 4; ++i)
        #pragma unroll
        for (int j = 0; j < 2; ++j)
            #pragma unroll
            for (int r = 0; r < 4; ++r) {
                int row = m0 + wm + i * 16 + l4 * 4 + r;
                int col = n0 + wn + j * 16 + l15;
                out[(size_t)row * EB + col] = acc[i][j][r] + bias[col];
            }
}

// ============================ launch ============================
extern "C" void kernel_launch(void* const* d_in, const int* in_sizes, int n_in,
                              void* d_out, int out_size, void* d_ws, size_t ws_size,
                              hipStream_t stream) {
    const float* values  = (const float*)d_in[0];
    const float* keys    = (const float*)d_in[1];
    const float* queries = (const float*)d_in[2];
    // d_in[3] = mask: analytic band |i-j| <= 64, not read
    const float* w_out   = (const float*)d_in[4];
    const float* b_out   = (const float*)d_in[5];
    float* out = (float*)d_out;

    ushort_t* X  = (ushort_t*)d_ws;                          // 4096*1024 bf16 = 8 MB
    ushort_t* Wb = (ushort_t*)d_ws + (size_t)4096 * 1024;    // 1024*1024 bf16 = 2 MB

    cvtw_kernel<<<(EB * EB / 4) / 256, 256, 0, stream>>>(w_out, Wb);
    attn_kernel<<<2 * HB * (SB / QT), 256, 0, stream>>>(values, keys, queries, X);
    proj_kernel<<<dim3(4096 / 128, EB / 128), 512, 0, stream>>>(X, Wb, b_out, out);
}

// Round 2
// 137.199 us; speedup vs baseline: 1.0767x; 1.0767x over previous
//
#include <hip/hip_runtime.h>

typedef __bf16 bf16x8 __attribute__((ext_vector_type(8)));
typedef float floatx4 __attribute__((ext_vector_type(4)));
typedef unsigned short ushortx8 __attribute__((ext_vector_type(8)));
typedef unsigned short ushortx4 __attribute__((ext_vector_type(4)));
typedef unsigned short ushort_t;

// ---- constants (from reference) ----
#define SB 2048      // sequence length
#define EB 1024      // embed
#define HB 16        // heads
#define DB 64        // head dim
#define QT 128       // queries per attention block (8 waves x 16)
#define KB2 256      // staged key band per block (64 halo each side)
#define KROW 72      // K lds row stride (bf16 elems)
#define VROW 272     // Vt row stride (256 keys + 16 zero pad), mult of 8
#define PROW 168     // P row stride (160 keys incl zero tile + pad), mult of 8

__device__ __forceinline__ ushort_t f2bf(float f) {
    union { float f; unsigned int u; } v; v.f = f;
    unsigned int r = v.u + 0x7fffu + ((v.u >> 16) & 1u);   // RNE
    return (ushort_t)(r >> 16);
}

union BF8 { ushortx8 u; bf16x8 b; };

// ============================ w_out -> bf16 ============================
__global__ __launch_bounds__(256) void cvtw_kernel(const float* __restrict__ w,
                                                   ushort_t* __restrict__ wb) {
    int i = blockIdx.x * 256 + threadIdx.x;          // over E*E/4 float4s
    const float4 v = ((const float4*)w)[i];
    ushortx4 o;
    o.x = f2bf(v.x); o.y = f2bf(v.y); o.z = f2bf(v.z); o.w = f2bf(v.w);
    ((ushortx4*)wb)[i] = o;
}

// ============================ attention ============================
// grid: B*H*(S/QT) = 2*16*16 = 512 blocks, 512 threads (8 waves).
// wave w handles queries [q0+16w, q0+16w+16); its keys live in band tiles
// [w, w+9) (144 keys), exactly covering the +-64 window of its 16 queries.
__global__ __launch_bounds__(512) void attn_kernel(const float* __restrict__ Vg,
                                                   const float* __restrict__ Kg,
                                                   const float* __restrict__ Qg,
                                                   ushort_t* __restrict__ Xg) {
    __shared__ ushort_t KP[8 * 16 * PROW];    // 43008 B; K band first, P later
    __shared__ ushort_t Vt[DB * VROW];        // 34816 B (V transposed: [dim][key])

    const int tid  = threadIdx.x;
    const int wave = tid >> 6;
    const int lane = tid & 63;
    const int l15  = lane & 15;
    const int l4   = lane >> 4;

    const int qt = blockIdx.x & 15;
    const int h  = (blockIdx.x >> 4) & 15;
    const int b  = blockIdx.x >> 8;

    const int q0     = qt * QT;
    const int kstart = q0 - 64;

    const float* Kbase = Kg + ((size_t)b * SB) * EB + h * DB;
    const float* Vbase = Vg + ((size_t)b * SB) * EB + h * DB;

    // ---- stage K band (row-major) and V band (transposed) into LDS as bf16 ----
    #pragma unroll
    for (int it = 0; it < (KB2 * DB / 4) / 512; ++it) {   // 8 iters of float4
        int idx = it * 512 + tid;
        int j   = idx >> 4;            // key slot 0..255
        int d4  = (idx & 15) * 4;      // dim 0..60
        int kk  = kstart + j;
        float4 kv = make_float4(0.f, 0.f, 0.f, 0.f);
        float4 vv = make_float4(0.f, 0.f, 0.f, 0.f);
        if (kk >= 0 && kk < SB) {
            kv = *(const float4*)(Kbase + (size_t)kk * EB + d4);
            vv = *(const float4*)(Vbase + (size_t)kk * EB + d4);
        }
        ushortx4 ku;
        ku.x = f2bf(kv.x); ku.y = f2bf(kv.y); ku.z = f2bf(kv.z); ku.w = f2bf(kv.w);
        *(ushortx4*)(KP + j * KROW + d4) = ku;
        Vt[(d4 + 0) * VROW + j] = f2bf(vv.x);
        Vt[(d4 + 1) * VROW + j] = f2bf(vv.y);
        Vt[(d4 + 2) * VROW + j] = f2bf(vv.z);
        Vt[(d4 + 3) * VROW + j] = f2bf(vv.w);
    }
    // zero Vt pad columns [256,272) so the zero-padded PV tile can't hit NaN
    {
        int r = tid >> 3, c = 256 + ((tid & 7) * 2);
        if (r < DB) { Vt[r * VROW + c] = 0; Vt[r * VROW + c + 1] = 0; }
    }

    // ---- Q fragments straight from global (A-layout: m=l15, k=l4*8+j) ----
    const int qrow = q0 + wave * 16 + l15;
    const float* Qrow = Qg + ((size_t)b * SB + qrow) * EB + h * DB;
    bf16x8 qfrag[2];
    #pragma unroll
    for (int ks = 0; ks < 2; ++ks) {
        const float4* p = (const float4*)(Qrow + ks * 32 + l4 * 8);
        float4 a0 = p[0], a1 = p[1];
        BF8 t;
        t.u[0] = f2bf(a0.x); t.u[1] = f2bf(a0.y); t.u[2] = f2bf(a0.z); t.u[3] = f2bf(a0.w);
        t.u[4] = f2bf(a1.x); t.u[5] = f2bf(a1.y); t.u[6] = f2bf(a1.z); t.u[7] = f2bf(a1.w);
        qfrag[ks] = t.b;
    }

    __syncthreads();

    // ---- S = Q K^T : M=16 (queries), N=144 (9 tiles at band offset w), K=64 ----
    floatx4 sfrag[9];
    #pragma unroll
    for (int nt = 0; nt < 9; ++nt) {
        floatx4 acc = {0.f, 0.f, 0.f, 0.f};
        #pragma unroll
        for (int ks = 0; ks < 2; ++ks) {
            bf16x8 kf = *(const bf16x8*)(KP + (16 * (wave + nt) + l15) * KROW + ks * 32 + l4 * 8);
            acc = __builtin_amdgcn_mfma_f32_16x16x32_bf16(qfrag[ks], kf, acc, 0, 0, 0);
        }
        sfrag[nt] = acc;
    }

    // ---- mask + scale (folded into exp2 base); softmax per row ----
    // row = l4*4 + r (query within wave), cols across 16 lanes
    const float scale2 = 0.04508421903306637f;   // (1/32) * log2(e)
    #pragma unroll
    for (int nt = 0; nt < 9; ++nt) {
        int key = kstart + 16 * (wave + nt) + l15;
        #pragma unroll
        for (int r = 0; r < 4; ++r) {
            int m = l4 * 4 + r;
            int d = 16 * nt + l15 - m;            // key - query + 64
            bool valid = (d >= 0) && (d <= 128) && (key >= 0) && (key < SB);
            float s = sfrag[nt][r] * scale2;
            sfrag[nt][r] = valid ? s : -1e30f;
        }
    }
    #pragma unroll
    for (int r = 0; r < 4; ++r) {
        float mx = -1e30f;
        #pragma unroll
        for (int nt = 0; nt < 9; ++nt) mx = fmaxf(mx, sfrag[nt][r]);
        mx = fmaxf(mx, __shfl_xor(mx, 1));
        mx = fmaxf(mx, __shfl_xor(mx, 2));
        mx = fmaxf(mx, __shfl_xor(mx, 4));
        mx = fmaxf(mx, __shfl_xor(mx, 8));
        float sum = 0.f;
        #pragma unroll
        for (int nt = 0; nt < 9; ++nt) {
            float e = exp2f(sfrag[nt][r] - mx);
            sfrag[nt][r] = e;
            sum += e;
        }
        sum += __shfl_xor(sum, 1);
        sum += __shfl_xor(sum, 2);
        sum += __shfl_xor(sum, 4);
        sum += __shfl_xor(sum, 8);
        float inv = 1.f / sum;
        #pragma unroll
        for (int nt = 0; nt < 9; ++nt) sfrag[nt][r] *= inv;
    }

    // ---- P: C/D layout -> A layout via LDS (overwrites K region) ----
    __syncthreads();                              // all waves done reading K
    ushort_t* Pw = KP + wave * (16 * PROW);       // 16 rows x PROW per wave
    #pragma unroll
    for (int nt = 0; nt < 9; ++nt)
        #pragma unroll
        for (int r = 0; r < 4; ++r)
            Pw[(l4 * 4 + r) * PROW + nt * 16 + l15] = f2bf(sfrag[nt][r]);
    // zero pad columns [144,168) of each P row (tile 9 + alignment pad)
    #pragma unroll
    for (int r = 0; r < 4; ++r) {
        int row = l4 * 4 + r;
        // 24 pad cols, 16 lanes: lanes 0..11 write 2 each
        if (l15 < 12) {
            Pw[row * PROW + 144 + l15 * 2]     = 0;
            Pw[row * PROW + 144 + l15 * 2 + 1] = 0;
        }
    }
    __syncthreads();

    // ---- O = P V : M=16, N=64 (4 tiles), K=160 (5 steps; last 16 cols are zero) ----
    #pragma unroll
    for (int nt = 0; nt < 4; ++nt) {
        floatx4 acc = {0.f, 0.f, 0.f, 0.f};
        #pragma unroll
        for (int ks = 0; ks < 5; ++ks) {
            bf16x8 pf = *(const bf16x8*)(Pw + l15 * PROW + ks * 32 + l4 * 8);
            bf16x8 vf = *(const bf16x8*)(Vt + (nt * 16 + l15) * VROW + 16 * wave + ks * 32 + l4 * 8);
            acc = __builtin_amdgcn_mfma_f32_16x16x32_bf16(pf, vf, acc, 0, 0, 0);
        }
        // write X (bf16): row = q, col = h*64 + nt*16 + l15
        #pragma unroll
        for (int r = 0; r < 4; ++r) {
            int q  = q0 + wave * 16 + l4 * 4 + r;
            int dd = h * DB + nt * 16 + l15;
            Xg[((size_t)b * SB + q) * EB + dd] = f2bf(acc[r]);
        }
    }
}

// ============================ projection GEMM ============================
// out[i][o] = sum_k X[i][k] * W[o][k] + bias[o]
// M=4096, N=1024, K=1024. BM=64, BN=128, BK=32 -> 512 blocks (2/CU), 256 thr.
__device__ __forceinline__ void async_load16(const void* g, void* l) {
    __builtin_amdgcn_global_load_lds((__attribute__((address_space(1))) void*)g,
                                     (__attribute__((address_space(3))) void*)l,
                                     16, 0, 0);
}

__global__ __launch_bounds__(256) void proj_kernel(const ushort_t* __restrict__ X,
                                                   const ushort_t* __restrict__ Wb,
                                                   const float* __restrict__ bias,
                                                   float* __restrict__ out) {
    __shared__ ushort_t As[64 * 32];    // 4096 B
    __shared__ ushort_t Bs[128 * 32];   // 8192 B

    const int tid  = threadIdx.x;
    const int wave = tid >> 6;
    const int lane = tid & 63;
    const int l15  = lane & 15;
    const int l4   = lane >> 4;

    const int m0 = blockIdx.x * 64;
    const int n0 = blockIdx.y * 128;
    const int wm = (wave >> 1) * 32;    // 2 wave-rows
    const int wn = (wave & 1) * 64;     // 2 wave-cols

    floatx4 acc[2][4];
    #pragma unroll
    for (int i = 0; i < 2; ++i)
        #pragma unroll
        for (int j = 0; j < 4; ++j)
            acc[i][j] = (floatx4){0.f, 0.f, 0.f, 0.f};

    // staging (16B chunks; LDS dest = wave-uniform base + lane*16B):
    // A: chunk cA = wave*64 + lane          -> row cA>>2, col (cA&3)*8
    // B: chunks cB = wave*128 + p*64 + lane -> row cB>>2, col (cB&3)*8, p in {0,1}
    const int cA  = wave * 64 + lane;
    const int cB0 = wave * 128 + lane;
    const ushort_t* gA  = X  + (size_t)(m0 + (cA >> 2)) * EB + (cA & 3) * 8;
    const ushort_t* gB0 = Wb + (size_t)(n0 + (cB0 >> 2)) * EB + (cB0 & 3) * 8;
    const ushort_t* gB1 = Wb + (size_t)(n0 + ((cB0 + 64) >> 2)) * EB + ((cB0 + 64) & 3) * 8;
    ushort_t* lA  = As + wave * 512;
    ushort_t* lB0 = Bs + wave * 1024;
    ushort_t* lB1 = Bs + wave * 1024 + 512;

    for (int kt = 0; kt < EB / 32; ++kt) {
        async_load16(gA,  lA);
        async_load16(gB0, lB0);
        async_load16(gB1, lB1);
        gA += 32; gB0 += 32; gB1 += 32;
        __syncthreads();                // drains vmcnt -> LDS valid

        bf16x8 af[2], bfr[4];
        #pragma unroll
        for (int i = 0; i < 2; ++i)
            af[i] = *(const bf16x8*)(As + (wm + i * 16 + l15) * 32 + l4 * 8);
        #pragma unroll
        for (int j = 0; j < 4; ++j)
            bfr[j] = *(const bf16x8*)(Bs + (wn + j * 16 + l15) * 32 + l4 * 8);
        #pragma unroll
        for (int i = 0; i < 2; ++i)
            #pragma unroll
            for (int j = 0; j < 4; ++j)
                acc[i][j] = __builtin_amdgcn_mfma_f32_16x16x32_bf16(af[i], bfr[j], acc[i][j], 0, 0, 0);
        __syncthreads();                // done reading before next stage
    }

    #pragma unroll
    for (int i = 0; i < 2; ++i)
        #pragma unroll
        for (int j = 0; j < 4; ++j)
            #pragma unroll
            for (int r = 0; r < 4; ++r) {
                int row = m0 + wm + i * 16 + l4 * 4 + r;
                int col = n0 + wn + j * 16 + l15;
                out[(size_t)row * EB + col] = acc[i][j][r] + bias[col];
            }
}

// ============================ launch ============================
extern "C" void kernel_launch(void* const* d_in, const int* in_sizes, int n_in,
                              void* d_out, int out_size, void* d_ws, size_t ws_size,
                              hipStream_t stream) {
    const float* values  = (const float*)d_in[0];
    const float* keys    = (const float*)d_in[1];
    const float* queries = (const float*)d_in[2];
    // d_in[3] = mask: analytic band |i-j| <= 64, not read
    const float* w_out   = (const float*)d_in[4];
    const float* b_out   = (const float*)d_in[5];
    float* out = (float*)d_out;

    ushort_t* Xb = (ushort_t*)d_ws;                          // 4096*1024 bf16 = 8 MB
    ushort_t* Wb = (ushort_t*)d_ws + (size_t)4096 * 1024;    // 1024*1024 bf16 = 2 MB

    cvtw_kernel<<<(EB * EB / 4) / 256, 256, 0, stream>>>(w_out, Wb);
    attn_kernel<<<2 * HB * (SB / QT), 512, 0, stream>>>(values, keys, queries, Xb);
    proj_kernel<<<dim3(4096 / 64, EB / 128), 256, 0, stream>>>(Xb, Wb, b_out, out);
}